// Round 19
// baseline (6543.118 us; speedup 1.0000x reference)
//
#include <hip/hip_runtime.h>
#include <hip/hip_bf16.h>
#include <math.h>

typedef unsigned short ushortT;
typedef unsigned int uintT;

// Problem constants
#define Bc   2
#define Tc   512
#define Cc   768
#define Hc   12
#define HDc  64
#define Vc   50304
#define BTc  (Bc*Tc)          // 1024
#define NHc  (Bc*Hc)          // 24
#define C3   (3*Cc)           // 2304
#define C4   (4*Cc)           // 3072
#define EPS_LN 1e-5f
#define H_STEP 0.05f
#define INVN (1.0f/512.0f)
#define SBQ  8                // blocks per head in sinkhorn (64 rows each)
#define ELP  (Tc + 8)         // padded Els leading dim
#define VLP  136              // PV V-tile leading dim (t-pad; 2-way bank class)

typedef float f32x4 __attribute__((ext_vector_type(4)));
typedef __bf16 bf16x8 __attribute__((ext_vector_type(8)));
typedef ushortT us8 __attribute__((ext_vector_type(8)));
typedef uintT u32x4 __attribute__((ext_vector_type(4)));

// ---------------- bf16 helpers --------------------------------------------
__device__ __forceinline__ ushortT f2bf(float f) {
    union { float f; unsigned u; } x; x.f = f;
    unsigned r = (x.u + 0x7fffu + ((x.u >> 16) & 1u)) >> 16;
    return (ushortT)r;
}
__device__ __forceinline__ float bf2f(ushortT b) {
    union { unsigned u; float f; } x; x.u = ((unsigned)b) << 16;
    return x.f;
}
__device__ __forceinline__ float bflo(uintT w) {
    union { unsigned u; float f; } x; x.u = w << 16;
    return x.f;
}
__device__ __forceinline__ float bfhi(uintT w) {
    union { unsigned u; float f; } x; x.u = w & 0xffff0000u;
    return x.f;
}

// async global->LDS, 16 bytes per lane (LDS dest lane-linear: base + lane*16)
__device__ __forceinline__ void gll16(const ushortT* g, ushortT* l) {
    __builtin_amdgcn_global_load_lds(
        (const __attribute__((address_space(1))) unsigned int*)g,
        (__attribute__((address_space(3))) unsigned int*)l,
        16, 0, 0);
}

// ---------------- wave reductions -----------------------------------------
__device__ __forceinline__ float waveReduceSumX(float v) {
    for (int o = 32; o; o >>= 1) v += __shfl_xor(v, o);
    return v;
}
__device__ __forceinline__ float blockReduceSum(float v) {
    __shared__ float sm[4];
    for (int o = 32; o; o >>= 1) v += __shfl_down(v, o);
    __syncthreads();
    if ((threadIdx.x & 63) == 0) sm[threadIdx.x >> 6] = v;
    __syncthreads();
    return sm[0] + sm[1] + sm[2] + sm[3];
}

// ---------------- weight fp32 [K][N] -> bf16 [N][K] transpose -------------
__global__ __launch_bounds__(256)
void wtrans_kernel(const float* __restrict__ W, ushortT* __restrict__ out,
                   int K, int N)
{
    __shared__ float t[32][33];
    int k0 = blockIdx.x * 32, n0 = blockIdx.y * 32;
    int tx = threadIdx.x & 31, ty = threadIdx.x >> 5;
    for (int r = ty; r < 32; r += 8)
        t[r][tx] = W[(size_t)(k0 + r) * N + n0 + tx];
    __syncthreads();
    for (int r = ty; r < 32; r += 8)
        out[(size_t)(n0 + r) * K + k0 + tx] = f2bf(t[tx][r]);
}

// ---------------- embed + attn-LN (t=0): z, xlnb, xt ----------------------
__global__ __launch_bounds__(256)
void embed_ln(const int* __restrict__ idx, const float* __restrict__ wte,
              const float* __restrict__ wpe, float* __restrict__ z,
              const float* __restrict__ lnw, const float* __restrict__ lnb,
              ushortT* __restrict__ xlnb, float* __restrict__ xt)
{
    int row = blockIdx.x, tid = threadIdx.x;
    int tok = idx[row];
    float v[3];
#pragma unroll
    for (int q = 0; q < 3; ++q) {
        int c = tid + 256 * q;
        float val = wte[(size_t)tok * Cc + c] + wpe[(size_t)(row & (Tc - 1)) * Cc + c];
        z[(size_t)row * Cc + c] = val;
        v[q] = val;
    }
    float s = blockReduceSum(v[0] + v[1] + v[2]);
    float mu = s / 769.f;                       // + t(=0)
    float d0 = v[0] - mu, d1 = v[1] - mu, d2 = v[2] - mu;
    float ss = blockReduceSum(d0 * d0 + d1 * d1 + d2 * d2);
    float dt = 0.f - mu;
    float var = (ss + dt * dt) / 769.f;
    float rs = rsqrtf(var + EPS_LN);
#pragma unroll
    for (int q = 0; q < 3; ++q) {
        int c = tid + 256 * q;
        xlnb[(size_t)row * Cc + c] = f2bf((v[q] - mu) * rs * lnw[c] + lnb[c]);
    }
    if (tid == 0) xt[row] = dt * rs * lnw[Cc] + lnb[Cc];
}

// -------- LayerNorm over 768 dims (+opt time col), fp32 OR bf16 input -----
__global__ __launch_bounds__(256)
void ln_kernel(const void* __restrict__ X, const float* __restrict__ w,
               const float* __restrict__ bb, void* __restrict__ Y,
               float* __restrict__ yt, int hasT, float tval,
               int rowMul, int rowAdd, int obf16, int ibf16)
{
    int orow = blockIdx.x;
    int r = orow * rowMul + rowAdd;
    int tid = threadIdx.x;
    float xv[3];
    if (ibf16) {
        const ushortT* x = (const ushortT*)X + (size_t)r * Cc;
#pragma unroll
        for (int q = 0; q < 3; ++q) xv[q] = bf2f(x[tid + 256 * q]);
    } else {
        const float* x = (const float*)X + (size_t)r * Cc;
#pragma unroll
        for (int q = 0; q < 3; ++q) xv[q] = x[tid + 256 * q];
    }
    float s = blockReduceSum(xv[0] + xv[1] + xv[2]);
    float cnt = hasT ? 769.f : 768.f;
    float mu = (s + (hasT ? tval : 0.f)) / cnt;
    float d0 = xv[0] - mu, d1 = xv[1] - mu, d2 = xv[2] - mu;
    float ss = blockReduceSum(d0 * d0 + d1 * d1 + d2 * d2);
    float dt = tval - mu;
    float var = (ss + (hasT ? dt * dt : 0.f)) / cnt;
    float rs = rsqrtf(var + EPS_LN);
#pragma unroll
    for (int q = 0; q < 3; ++q) {
        int c = tid + 256 * q;
        float v = (xv[q] - mu) * rs * w[c] + bb[c];
        if (obf16) ((ushortT*)Y)[(size_t)orow * Cc + c] = f2bf(v);
        else       ((float*)Y)[(size_t)orow * Cc + c] = v;
    }
    if (hasT && tid == 0) yt[orow] = dt * rs * w[Cc] + bb[Cc];
}

// ---------------- MFMA GEMM: C = A[M,K](bf16) @ Bt[N,K](bf16)^T -----------
// BK=64, XOR-swizzled LDS. EPI: 0 = bias(+rank1) -> bf16 ;
// 1 = gelu(bias+rank1) -> bf16 ; 4 = split-K partial fp32
template <int EPI>
__global__ __launch_bounds__(256)
void gemm_bt(const ushortT* __restrict__ A, int lda,
             const ushortT* __restrict__ Bt, int ldb,
             void* __restrict__ Cm, int ldc, int K,
             const float* __restrict__ bias,
             const float* __restrict__ extraA,
             const float* __restrict__ extraB)
{
    __shared__ __align__(16) ushortT Als[128 * 64];   // 16 KB, swizzled linear
    __shared__ __align__(16) ushortT Bls[128 * 64];   // 16 KB
    if (EPI == 4) {
        int koff = blockIdx.z * K;
        A += koff; Bt += koff;
    }
    int tid = threadIdx.x;
    int lane = tid & 63, wid = tid >> 6;
    int wm = wid >> 1, wn = wid & 1;
    int m0 = blockIdx.y * 128, n0 = blockIdx.x * 128;
    f32x4 acc[4][4];
    const f32x4 fz = {0.f, 0.f, 0.f, 0.f};
#pragma unroll
    for (int i = 0; i < 4; ++i)
#pragma unroll
        for (int j = 0; j < 4; ++j) acc[i][j] = fz;

    for (int k0 = 0; k0 < K; k0 += 64) {
#pragma unroll
        for (int is = 0; is < 4; ++is) {
            int ch = is * 256 + tid;              // 0..1023
            int m = ch >> 3;
            int kc8 = (ch & 7) ^ (m & 7);         // pre-swizzled source chunk
            gll16(A + (size_t)(m0 + m) * lda + k0 + kc8 * 8, Als + ch * 8);
            gll16(Bt + (size_t)(n0 + m) * ldb + k0 + kc8 * 8, Bls + ch * 8);
        }
        __syncthreads();
#pragma unroll
        for (int kk = 0; kk < 2; ++kk) {
            int cidx = kk * 4 + (lane >> 4);
            bf16x8 af[4], bfv[4];
#pragma unroll
            for (int i = 0; i < 4; ++i) {
                int row = wm * 64 + i * 16 + (lane & 15);
                af[i] = *(const bf16x8*)(Als + ((size_t)row * 8 + (cidx ^ (row & 7))) * 8);
                int col = wn * 64 + i * 16 + (lane & 15);
                bfv[i] = *(const bf16x8*)(Bls + ((size_t)col * 8 + (cidx ^ (col & 7))) * 8);
            }
#pragma unroll
            for (int i = 0; i < 4; ++i)
#pragma unroll
                for (int j = 0; j < 4; ++j)
                    acc[i][j] = __builtin_amdgcn_mfma_f32_16x16x32_bf16(af[i], bfv[j], acc[i][j], 0, 0, 0);
        }
        __syncthreads();
    }
#pragma unroll
    for (int i = 0; i < 4; ++i) {
#pragma unroll
        for (int j = 0; j < 4; ++j) {
#pragma unroll
            for (int r = 0; r < 4; ++r) {
                int row = m0 + wm * 64 + i * 16 + (lane >> 4) * 4 + r;
                int col = n0 + wn * 64 + j * 16 + (lane & 15);
                float v = acc[i][j][r];
                if (extraA) v += extraA[row] * extraB[col];
                if (bias) v += bias[col];
                size_t oi = (size_t)row * ldc + col;
                if (EPI == 0) {
                    ((ushortT*)Cm)[oi] = f2bf(v);
                } else if (EPI == 1) {
                    v = 0.5f * v * (1.f + erff(v * 0.70710678118654752440f));
                    ((ushortT*)Cm)[oi] = f2bf(v);
                } else if (EPI == 4) {
                    ((float*)Cm)[(size_t)blockIdx.z * ((size_t)BTc * Cc) + oi] = v;
                }
            }
        }
    }
}

// ===== fused QK + softmax + Sinkhorn + PV (per-head-eighth block) ==========
// grid = 192 blocks x 512 threads. Block (n = gb%24, r = gb/24) owns rows
// [r*64, r*64+64) of head n; all 8 blocks of head n land on XCD n%8.
// Cross-block exchange: all-thread acquire-polling (no broadcast barriers),
// release-add counter signal.
__global__ __launch_bounds__(512)
void sinkfused(const ushortT* __restrict__ qkvb, ushortT* __restrict__ y,
               float* __restrict__ partials, unsigned* __restrict__ ctr,
               unsigned barBase)
{
    int gb = blockIdx.x;
    int n = gb % NHc, r = gb / NHc;
    int row0 = r * 64;
    int b = n / Hc, h = n - b * Hc;
    int tid = threadIdx.x;
    int l = tid & 63, w = tid >> 6;              // 8 waves
    int wm = w >> 1, wn = w & 1;                 // 4 row-groups x 2 col-groups
    __shared__ __align__(16) ushortT Els[64][ELP];    // 66.6 KB (padded)
    __shared__ __align__(16) ushortT Kshare[64 * VLP]; // 17.4 KB (scratch / PV V)
    __shared__ float a_s[64];
    __shared__ float b_s[Tc];
    __shared__ float smx[2][64], ssum[2][64], srs[2][64];
    const f32x4 fz = {0.f, 0.f, 0.f, 0.f};

    // ---- phase QK: scores for own 64 rows x (r+1)*64 cols ----
    int qrow = b * Tc + row0 + wm * 16 + (l & 15);
    const ushortT* qp = qkvb + (size_t)qrow * C3 + h * HDc + (l >> 4) * 8;
    bf16x8 aq0 = *(const bf16x8*)(qp);
    bf16x8 aq1 = *(const bf16x8*)(qp + 32);

    int nT2 = (r + 1) * 2;                       // col-tiles per wn (<=16)
    f32x4 acc[16];
#pragma unroll
    for (int j = 0; j < 16; ++j) acc[j] = fz;

    // stage ALL K rows [0, (r+1)*64) swizzled into Els region (<=64KB)
    ushortT* EK = &Els[0][0];
    {
        int nch = (r + 1) * 512;                  // rows*8 chunks
        for (int ch = tid; ch < nch; ch += 512) {
            int row = ch >> 3, c16 = (ch & 7) ^ (row & 7);
            gll16(qkvb + (size_t)(b * Tc + row) * C3 + Cc + h * HDc + c16 * 8,
                  EK + ch * 8);
        }
    }
    __syncthreads();
#pragma unroll
    for (int t = 0; t < 16; ++t) {
        if (t < nT2) {
            int krow = (2 * t + wn) * 16 + (l & 15);
            int c16a = (l >> 4);
            int c16b = 4 + (l >> 4);
            bf16x8 bk0 = *(const bf16x8*)(EK + ((size_t)krow * 8 + (c16a ^ (krow & 7))) * 8);
            bf16x8 bk1 = *(const bf16x8*)(EK + ((size_t)krow * 8 + (c16b ^ (krow & 7))) * 8);
            acc[t] = __builtin_amdgcn_mfma_f32_16x16x32_bf16(aq0, bk0, acc[t], 0, 0, 0);
            acc[t] = __builtin_amdgcn_mfma_f32_16x16x32_bf16(aq1, bk1, acc[t], 0, 0, 0);
        }
    }
    __syncthreads();   // all EK reads done before Els is overwritten below

    // ---- causal softmax (rows split across wn pairs) -> E, rowsum -> a1 --
    int colbase = (l & 15);
    int lrow4 = wm * 16 + (l >> 4) * 4;          // local row base for e=0..3
    int rowa[4];
#pragma unroll
    for (int e = 0; e < 4; ++e) rowa[e] = row0 + lrow4 + e;

    float mx[4] = {-INFINITY, -INFINITY, -INFINITY, -INFINITY};
#pragma unroll
    for (int t = 0; t < 16; ++t) {
        if (t < nT2) {
            int col = (2 * t + wn) * 16 + colbase;
#pragma unroll
            for (int e = 0; e < 4; ++e)
                if (col <= rowa[e]) mx[e] = fmaxf(mx[e], acc[t][e] * 0.125f);
        }
    }
#pragma unroll
    for (int e = 0; e < 4; ++e)
        for (int o = 1; o < 16; o <<= 1) mx[e] = fmaxf(mx[e], __shfl_xor(mx[e], o));
    if ((l & 15) == 0)
#pragma unroll
        for (int e = 0; e < 4; ++e) smx[wn][lrow4 + e] = mx[e];
    __syncthreads();
#pragma unroll
    for (int e = 0; e < 4; ++e)
        mx[e] = fmaxf(smx[0][lrow4 + e], smx[1][lrow4 + e]);

    float se[4] = {0.f, 0.f, 0.f, 0.f};
#pragma unroll
    for (int t = 0; t < 16; ++t) {
        if (t < nT2) {
            int col = (2 * t + wn) * 16 + colbase;
#pragma unroll
            for (int e = 0; e < 4; ++e) {
                float exv = (col <= rowa[e]) ? __expf(acc[t][e] * 0.125f - mx[e]) : 0.f;
                acc[t][e] = exv;
                se[e] += exv;
            }
        }
    }
#pragma unroll
    for (int e = 0; e < 4; ++e)
        for (int o = 1; o < 16; o <<= 1) se[e] += __shfl_xor(se[e], o);
    if ((l & 15) == 0)
#pragma unroll
        for (int e = 0; e < 4; ++e) ssum[wn][lrow4 + e] = se[e];
    __syncthreads();
    float inv[4];
#pragma unroll
    for (int e = 0; e < 4; ++e)
        inv[e] = 1.f / (ssum[0][lrow4 + e] + ssum[1][lrow4 + e]);

    float rsum[4] = {0.f, 0.f, 0.f, 0.f};
#pragma unroll
    for (int t = 0; t < 16; ++t) {
        if (t < nT2) {
            int col = (2 * t + wn) * 16 + colbase;
#pragma unroll
            for (int e = 0; e < 4; ++e) {
                float Ee = __expf(-(acc[t][e] * inv[e]));   // masked: exp(-0)=1
                rsum[e] += Ee;
                Els[lrow4 + e][col] = f2bf(Ee);
            }
        }
    }
#pragma unroll
    for (int e = 0; e < 4; ++e)
        for (int o = 1; o < 16; o <<= 1) rsum[e] += __shfl_xor(rsum[e], o);
    if ((l & 15) == 0)
#pragma unroll
        for (int e = 0; e < 4; ++e) srs[wn][lrow4 + e] = rsum[e];
    __syncthreads();
    if (wn == 0 && (l & 15) == 0) {
        float tail = (float)(Tc - (r + 1) * 64);
#pragma unroll
        for (int e = 0; e < 4; ++e)
            a_s[lrow4 + e] = INVN / (srs[0][lrow4 + e] + srs[1][lrow4 + e] + tail);
    }
    // fill fully-masked tail with ones
    {
        int tailc = 64 - (r + 1) * 8;             // us8 chunks per row
        if (tailc > 0) {
            us8 ones8;
#pragma unroll
            for (int e = 0; e < 8; ++e) ones8[e] = 0x3F80;
            for (int idx2 = tid; idx2 < 64 * tailc; idx2 += 512) {
                int rr = idx2 / tailc, cc = idx2 - rr * tailc;
                *(us8*)&Els[rr][((r + 1) * 8 + cc) * 8] = ones8;
            }
        }
    }
    __syncthreads();

    float* mypart = partials + (size_t)(n * SBQ + r) * Tc;
    const float* hpart = partials + (size_t)n * SBQ * Tc;
    unsigned* myctr = ctr + n * 16;              // 64B-padded per-head counter
    float* scr = (float*)Kshare;                 // 8 x 512 fp32 col-pass scratch

    // ---- 11 alternating passes: col(0),row(1),...,col(10) ----
#pragma unroll 1
    for (int p = 0; p < 11; ++p) {
        if ((p & 1) == 0) {
            // col partial over own 64 rows — vectorized us8 + scratch reduce
            int cg = tid & 63, sl = tid >> 6;
            float ac[8] = {0.f, 0.f, 0.f, 0.f, 0.f, 0.f, 0.f, 0.f};
#pragma unroll
            for (int i = 0; i < 8; ++i) {
                int row = sl * 8 + i;
                us8 ev = *(const us8*)&Els[row][cg * 8];
                float fa = a_s[row];
#pragma unroll
                for (int e = 0; e < 8; ++e)
                    ac[e] += bf2f(ev[e]) * fa;
            }
            f32x4 lo = {ac[0], ac[1], ac[2], ac[3]};
            f32x4 hi = {ac[4], ac[5], ac[6], ac[7]};
            *(f32x4*)&scr[sl * 512 + cg * 8] = lo;
            *(f32x4*)&scr[sl * 512 + cg * 8 + 4] = hi;
            __syncthreads();
            int j = tid;
            float accs = 0.f;
#pragma unroll
            for (int s2 = 0; s2 < 8; ++s2) accs += scr[s2 * 512 + j];
            __hip_atomic_store(&mypart[j], accs, __ATOMIC_RELAXED, __HIP_MEMORY_SCOPE_AGENT);
            __syncthreads();     // all block stores issued+complete before signal
            if (tid == 0)
                __hip_atomic_fetch_add(myctr, 1u, __ATOMIC_RELEASE, __HIP_MEMORY_SCOPE_AGENT);
            // all-thread acquire-poll: no broadcast barriers needed
            unsigned tgt = barBase + (unsigned)(p / 2 + 1) * SBQ;
            while (__hip_atomic_load(myctr, __ATOMIC_ACQUIRE, __HIP_MEMORY_SCOPE_AGENT) < tgt)
                __builtin_amdgcn_s_sleep(1);
            float accs2 = 0.f;
#pragma unroll
            for (int s2 = 0; s2 < SBQ; ++s2)
                accs2 += __hip_atomic_load(&hpart[s2 * Tc + j], __ATOMIC_RELAXED, __HIP_MEMORY_SCOPE_AGENT);
            b_s[j] = INVN / accs2;
            __syncthreads();
        } else {
            // row pass on own rows: wave per 8 rows, ILP 4
            f32x4 b0 = *(const f32x4*)&b_s[l * 8];
            f32x4 b1 = *(const f32x4*)&b_s[l * 8 + 4];
            float breg[8] = {b0[0], b0[1], b0[2], b0[3], b1[0], b1[1], b1[2], b1[3]};
#pragma unroll 1
            for (int k = 0; k < 8; k += 4) {
                int r0 = w * 8 + k;
                u32x4 q0 = *(const u32x4*)(&Els[r0 + 0][l * 8]);
                u32x4 q1 = *(const u32x4*)(&Els[r0 + 1][l * 8]);
                u32x4 q2 = *(const u32x4*)(&Els[r0 + 2][l * 8]);
                u32x4 q3 = *(const u32x4*)(&Els[r0 + 3][l * 8]);
                float s0 = 0.f, s1 = 0.f, s2 = 0.f, s3 = 0.f;
#pragma unroll
                for (int c = 0; c < 4; ++c) {
                    s0 += bflo(q0[c]) * breg[2 * c] + bfhi(q0[c]) * breg[2 * c + 1];
                    s1 += bflo(q1[c]) * breg[2 * c] + bfhi(q1[c]) * breg[2 * c + 1];
                    s2 += bflo(q2[c]) * breg[2 * c] + bfhi(q2[c]) * breg[2 * c + 1];
                    s3 += bflo(q3[c]) * breg[2 * c] + bfhi(q3[c]) * breg[2 * c + 1];
                }
                s0 = waveReduceSumX(s0);
                s1 = waveReduceSumX(s1);
                s2 = waveReduceSumX(s2);
                s3 = waveReduceSumX(s3);
                if (l == 0) {
                    a_s[r0 + 0] = INVN / s0;
                    a_s[r0 + 1] = INVN / s1;
                    a_s[r0 + 2] = INVN / s2;
                    a_s[r0 + 3] = INVN / s3;
                }
            }
            __syncthreads();
        }
    }

    // ---- PV (local, 128-t chunks): y = a6 ⊙ (E_own @ (n·b6 ⊙ V)) ---------
    {
        ushortT* Kls2 = Kshare;                  // [64 d][136 t-pad] bf16
        f32x4 acc2[2];
#pragma unroll
        for (int j = 0; j < 2; ++j) acc2[j] = fz;
        const ushortT* vbase = qkvb + (size_t)(b * Tc) * C3 + 2 * Cc + h * HDc;

#pragma unroll 1
        for (int k0 = 0; k0 < Tc; k0 += 128) {
            // stage chunk: 128 t x 64 d, scaled by n*b6[t], transposed
#pragma unroll
            for (int ii = 0; ii < 2; ++ii) {
                int ch = ii * 512 + tid;          // 0..1023
                int tt = ch >> 3, dblk = ch & 7;
                us8 vv = *(const us8*)(vbase + (size_t)(k0 + tt) * C3 + dblk * 8);
                float bs = 512.f * b_s[k0 + tt];
#pragma unroll
                for (int e = 0; e < 8; ++e)
                    Kls2[(dblk * 8 + e) * VLP + tt] = f2bf(bf2f(vv[e]) * bs);
            }
            __syncthreads();
#pragma unroll
            for (int kk = 0; kk < 128; kk += 32) {
                bf16x8 af = *(const bf16x8*)&Els[wm * 16 + (l & 15)][k0 + kk + (l >> 4) * 8];
#pragma unroll
                for (int j = 0; j < 2; ++j) {
                    bf16x8 bv = *(const bf16x8*)(Kls2 + (size_t)(wn * 32 + j * 16 + (l & 15)) * VLP + kk + (l >> 4) * 8);
                    acc2[j] = __builtin_amdgcn_mfma_f32_16x16x32_bf16(af, bv, acc2[j], 0, 0, 0);
                }
            }
            __syncthreads();
        }
#pragma unroll
        for (int j = 0; j < 2; ++j)
#pragma unroll
            for (int rr = 0; rr < 4; ++rr) {
                int lrow = wm * 16 + (l >> 4) * 4 + rr;
                float a_r = a_s[lrow];
                int grow = b * Tc + row0 + lrow;
                int gcol = h * HDc + wn * 32 + j * 16 + (l & 15);
                y[(size_t)grow * Cc + gcol] = f2bf(acc2[j][rr] * a_r);
            }
    }
}

// ------- split-K reduce + bias (+opt Euler) + LN (fused) ------------------
__global__ __launch_bounds__(256)
void reduce_ln(const float* __restrict__ parts, const float* __restrict__ bias,
               float* __restrict__ z, const float* __restrict__ lnw,
               const float* __restrict__ lnb, ushortT* __restrict__ xlnb,
               float* __restrict__ xt, float tval, int doEuler)
{
    int row = blockIdx.x, tid = threadIdx.x;
    const size_t CS = (size_t)BTc * Cc;
    float v[3];
#pragma unroll
    for (int q = 0; q < 3; ++q) {
        int c = tid + 256 * q;
        size_t idx = (size_t)row * Cc + c;
        float s = parts[idx] + parts[CS + idx] + parts[2 * CS + idx]
                + parts[3 * CS + idx] + bias[c];
        if (doEuler) {
            v[q] = z[idx] + H_STEP * s;
            z[idx] = v[q];
        } else {
            v[q] = s;
        }
    }
    float s = blockReduceSum(v[0] + v[1] + v[2]);
    float mu = (s + tval) / 769.f;
    float d0 = v[0] - mu, d1 = v[1] - mu, d2 = v[2] - mu;
    float ss = blockReduceSum(d0 * d0 + d1 * d1 + d2 * d2);
    float dt = tval - mu;
    float var = (ss + dt * dt) / 769.f;
    float rs = rsqrtf(var + EPS_LN);
#pragma unroll
    for (int q = 0; q < 3; ++q) {
        int c = tid + 256 * q;
        xlnb[(size_t)row * Cc + c] = f2bf((v[q] - mu) * rs * lnw[c] + lnb[c]);
    }
    if (tid == 0) xt[row] = dt * rs * lnw[Cc] + lnb[Cc];
}

// ---------------- logits: out[b,v] = xf[b,:] . wte[v,:] (fp32, f32x4) -----
__global__ __launch_bounds__(256)
void logits_kernel(const float* __restrict__ xf, const float* __restrict__ wte,
                   float* __restrict__ out)
{
    __shared__ __align__(16) float xs[2 * Cc];
    int tid = threadIdx.x;
    for (int i = tid; i < 384; i += 256)
        ((f32x4*)xs)[i] = ((const f32x4*)xf)[i];
    __syncthreads();
    int w = tid >> 6, lane = tid & 63;
    int vrow = blockIdx.x * 4 + w;
    const f32x4* wr = (const f32x4*)(wte + (size_t)vrow * Cc);
    const f32x4* x0 = (const f32x4*)xs;
    const f32x4* x1 = (const f32x4*)(xs + Cc);
    float a0 = 0.f, a1 = 0.f;
#pragma unroll
    for (int it = 0; it < 3; ++it) {
        int k4 = it * 64 + lane;
        f32x4 wv = wr[k4];
        f32x4 p = x0[k4], q = x1[k4];
        a0 += wv[0] * p[0] + wv[1] * p[1] + wv[2] * p[2] + wv[3] * p[3];
        a1 += wv[0] * q[0] + wv[1] * q[1] + wv[2] * q[2] + wv[3] * q[3];
    }
    for (int o = 32; o; o >>= 1) {
        a0 += __shfl_down(a0, o);
        a1 += __shfl_down(a1, o);
    }
    if (lane == 0) {
        out[vrow] = a0;
        out[Vc + vrow] = a1;
    }
}

// ==========================================================================
extern "C" void kernel_launch(void* const* d_in, const int* in_sizes, int n_in,
                              void* d_out, int out_size, void* d_ws, size_t ws_size,
                              hipStream_t stream)
{
    const int*   idx        = (const int*)  d_in[0];
    const float* wte        = (const float*)d_in[1];
    const float* wpe        = (const float*)d_in[2];
    const float* attn_ln_w  = (const float*)d_in[3];
    const float* attn_ln_b  = (const float*)d_in[4];
    const float* c_attn_w   = (const float*)d_in[5];
    const float* c_attn_b   = (const float*)d_in[6];
    const float* c_proj_w   = (const float*)d_in[7];
    const float* c_proj_b   = (const float*)d_in[8];
    const float* mlp_ln_w   = (const float*)d_in[9];
    const float* mlp_ln_b   = (const float*)d_in[10];
    const float* c_fc_w     = (const float*)d_in[11];
    const float* c_fc_b     = (const float*)d_in[12];
    const float* mlp_proj_w = (const float*)d_in[13];
    const float* mlp_proj_b = (const float*)d_in[14];
    const float* lnf_w      = (const float*)d_in[15];
    const float* lnf_b      = (const float*)d_in[16];
    float* out = (float*)d_out;

    // -------- workspace carving (256B aligned) --------
    char* base = (char*)d_ws;
    size_t off = 0;
    auto alloc = [&](size_t bytes) -> void* {
        void* p = base + off;
        off = (off + bytes + 255) & ~(size_t)255;
        return p;
    };
    float*   z     = (float*)  alloc((size_t)BTc * Cc * 4);
    float*   parts = (float*)  alloc((size_t)4 * BTc * Cc * 4);   // split-K partials
    ushortT* qkvb  = (ushortT*)alloc((size_t)BTc * C3 * 2);
    ushortT* xlnb  = (ushortT*)alloc((size_t)BTc * Cc * 2);
    ushortT* y     = (ushortT*)alloc((size_t)BTc * Cc * 2);
    ushortT* h1    = (ushortT*)alloc((size_t)BTc * C4 * 2);
    float*   xt    = (float*)  alloc(BTc * 4);
    float*   partv = (float*)  alloc((size_t)NHc * SBQ * Tc * 4);
    unsigned* ctr  = (unsigned*)alloc(NHc * 16 * 4);
    float*   xf    = (float*)  alloc(2 * Cc * 4);
    ushortT* WqkvT = (ushortT*)alloc((size_t)C3 * Cc * 2);
    ushortT* WprojT= (ushortT*)alloc((size_t)Cc * Cc * 2);
    ushortT* WfcT  = (ushortT*)alloc((size_t)C4 * Cc * 2);
    ushortT* WmlpT = (ushortT*)alloc((size_t)Cc * C4 * 2);

    hipMemsetAsync(ctr, 0, NHc * 16 * 4, stream);
    embed_ln<<<BTc, 256, 0, stream>>>(idx, wte, wpe, z, attn_ln_w, attn_ln_b, xlnb, xt);
    wtrans_kernel<<<dim3(Cc / 32, C3 / 32), 256, 0, stream>>>(c_attn_w,   WqkvT,  Cc, C3);
    wtrans_kernel<<<dim3(Cc / 32, Cc / 32), 256, 0, stream>>>(c_proj_w,   WprojT, Cc, Cc);
    wtrans_kernel<<<dim3(Cc / 32, C4 / 32), 256, 0, stream>>>(c_fc_w,     WfcT,   Cc, C4);
    wtrans_kernel<<<dim3(C4 / 32, Cc / 32), 256, 0, stream>>>(mlp_proj_w, WmlpT,  C4, Cc);

    float t = 0.f;
    for (int step = 0; step < 20; ++step) {
        gemm_bt<0><<<dim3(C3 / 128, BTc / 128), 256, 0, stream>>>(
            xlnb, Cc, WqkvT, Cc, qkvb, C3, Cc,
            c_attn_b, xt, c_attn_w + (size_t)Cc * C3);
        sinkfused<<<NHc * SBQ, 512, 0, stream>>>(
            qkvb, y, partv, ctr, (unsigned)(step * 6 * SBQ));
        gemm_bt<4><<<dim3(Cc / 128, BTc / 128, 4), 256, 0, stream>>>(
            y, Cc, WprojT, Cc, parts, Cc, Cc / 4,
            nullptr, nullptr, nullptr);
        reduce_ln<<<BTc, 256, 0, stream>>>(parts, c_proj_b, nullptr,
                                           mlp_ln_w, mlp_ln_b, xlnb, xt, t, 0);
        gemm_bt<1><<<dim3(C4 / 128, BTc / 128), 256, 0, stream>>>(
            xlnb, Cc, WfcT, Cc, h1, C4, Cc,
            c_fc_b, xt, c_fc_w + (size_t)Cc * C4);
        gemm_bt<4><<<dim3(Cc / 128, BTc / 128, 4), 256, 0, stream>>>(
            h1, C4, WmlpT, C4, parts, Cc, C4 / 4,
            nullptr, nullptr, nullptr);
        t += H_STEP;
        reduce_ln<<<BTc, 256, 0, stream>>>(parts, mlp_proj_b, z,
                                           attn_ln_w, attn_ln_b, xlnb, xt, t, 1);
    }

    ln_kernel<<<2, 256, 0, stream>>>(z, lnf_w, lnf_b, xf, nullptr, 0, 0.f, Tc, Tc - 1, 0, 0);
    logits_kernel<<<Vc / 4, 256, 0, stream>>>(xf, wte, out);
}

// Round 20
// 3402.543 us; speedup vs baseline: 1.9230x; 1.9230x over previous
//
#include <hip/hip_runtime.h>
#include <hip/hip_bf16.h>
#include <math.h>

typedef unsigned short ushortT;
typedef unsigned int uintT;

// Problem constants
#define Bc   2
#define Tc   512
#define Cc   768
#define Hc   12
#define HDc  64
#define Vc   50304
#define BTc  (Bc*Tc)          // 1024
#define NHc  (Bc*Hc)          // 24
#define C3   (3*Cc)           // 2304
#define C4   (4*Cc)           // 3072
#define EPS_LN 1e-5f
#define H_STEP 0.05f
#define INVN (1.0f/512.0f)
#define SBQ  8                // blocks per head in sinkhorn (64 rows each)
#define ELP  (Tc + 8)         // padded Els leading dim
#define VLP  136              // PV V-tile leading dim (t-pad; 2-way bank class)

typedef float f32x4 __attribute__((ext_vector_type(4)));
typedef __bf16 bf16x8 __attribute__((ext_vector_type(8)));
typedef ushortT us8 __attribute__((ext_vector_type(8)));
typedef uintT u32x4 __attribute__((ext_vector_type(4)));

// ---------------- bf16 helpers --------------------------------------------
__device__ __forceinline__ ushortT f2bf(float f) {
    union { float f; unsigned u; } x; x.f = f;
    unsigned r = (x.u + 0x7fffu + ((x.u >> 16) & 1u)) >> 16;
    return (ushortT)r;
}
__device__ __forceinline__ float bf2f(ushortT b) {
    union { unsigned u; float f; } x; x.u = ((unsigned)b) << 16;
    return x.f;
}
__device__ __forceinline__ float bflo(uintT w) {
    union { unsigned u; float f; } x; x.u = w << 16;
    return x.f;
}
__device__ __forceinline__ float bfhi(uintT w) {
    union { unsigned u; float f; } x; x.u = w & 0xffff0000u;
    return x.f;
}

// async global->LDS, 16 bytes per lane (LDS dest lane-linear: base + lane*16)
__device__ __forceinline__ void gll16(const ushortT* g, ushortT* l) {
    __builtin_amdgcn_global_load_lds(
        (const __attribute__((address_space(1))) unsigned int*)g,
        (__attribute__((address_space(3))) unsigned int*)l,
        16, 0, 0);
}

// ---------------- wave reductions -----------------------------------------
__device__ __forceinline__ float waveReduceSumX(float v) {
    for (int o = 32; o; o >>= 1) v += __shfl_xor(v, o);
    return v;
}
__device__ __forceinline__ float blockReduceSum(float v) {
    __shared__ float sm[4];
    for (int o = 32; o; o >>= 1) v += __shfl_down(v, o);
    __syncthreads();
    if ((threadIdx.x & 63) == 0) sm[threadIdx.x >> 6] = v;
    __syncthreads();
    return sm[0] + sm[1] + sm[2] + sm[3];
}

// ---------------- weight fp32 [K][N] -> bf16 [N][K] transpose -------------
__global__ __launch_bounds__(256)
void wtrans_kernel(const float* __restrict__ W, ushortT* __restrict__ out,
                   int K, int N)
{
    __shared__ float t[32][33];
    int k0 = blockIdx.x * 32, n0 = blockIdx.y * 32;
    int tx = threadIdx.x & 31, ty = threadIdx.x >> 5;
    for (int r = ty; r < 32; r += 8)
        t[r][tx] = W[(size_t)(k0 + r) * N + n0 + tx];
    __syncthreads();
    for (int r = ty; r < 32; r += 8)
        out[(size_t)(n0 + r) * K + k0 + tx] = f2bf(t[tx][r]);
}

// ---------------- embed + attn-LN (t=0): z, xlnb, xt ----------------------
__global__ __launch_bounds__(256)
void embed_ln(const int* __restrict__ idx, const float* __restrict__ wte,
              const float* __restrict__ wpe, float* __restrict__ z,
              const float* __restrict__ lnw, const float* __restrict__ lnb,
              ushortT* __restrict__ xlnb, float* __restrict__ xt)
{
    int row = blockIdx.x, tid = threadIdx.x;
    int tok = idx[row];
    float v[3];
#pragma unroll
    for (int q = 0; q < 3; ++q) {
        int c = tid + 256 * q;
        float val = wte[(size_t)tok * Cc + c] + wpe[(size_t)(row & (Tc - 1)) * Cc + c];
        z[(size_t)row * Cc + c] = val;
        v[q] = val;
    }
    float s = blockReduceSum(v[0] + v[1] + v[2]);
    float mu = s / 769.f;                       // + t(=0)
    float d0 = v[0] - mu, d1 = v[1] - mu, d2 = v[2] - mu;
    float ss = blockReduceSum(d0 * d0 + d1 * d1 + d2 * d2);
    float dt = 0.f - mu;
    float var = (ss + dt * dt) / 769.f;
    float rs = rsqrtf(var + EPS_LN);
#pragma unroll
    for (int q = 0; q < 3; ++q) {
        int c = tid + 256 * q;
        xlnb[(size_t)row * Cc + c] = f2bf((v[q] - mu) * rs * lnw[c] + lnb[c]);
    }
    if (tid == 0) xt[row] = dt * rs * lnw[Cc] + lnb[Cc];
}

// -------- LayerNorm over 768 dims (+opt time col), fp32 OR bf16 input -----
__global__ __launch_bounds__(256)
void ln_kernel(const void* __restrict__ X, const float* __restrict__ w,
               const float* __restrict__ bb, void* __restrict__ Y,
               float* __restrict__ yt, int hasT, float tval,
               int rowMul, int rowAdd, int obf16, int ibf16)
{
    int orow = blockIdx.x;
    int r = orow * rowMul + rowAdd;
    int tid = threadIdx.x;
    float xv[3];
    if (ibf16) {
        const ushortT* x = (const ushortT*)X + (size_t)r * Cc;
#pragma unroll
        for (int q = 0; q < 3; ++q) xv[q] = bf2f(x[tid + 256 * q]);
    } else {
        const float* x = (const float*)X + (size_t)r * Cc;
#pragma unroll
        for (int q = 0; q < 3; ++q) xv[q] = x[tid + 256 * q];
    }
    float s = blockReduceSum(xv[0] + xv[1] + xv[2]);
    float cnt = hasT ? 769.f : 768.f;
    float mu = (s + (hasT ? tval : 0.f)) / cnt;
    float d0 = xv[0] - mu, d1 = xv[1] - mu, d2 = xv[2] - mu;
    float ss = blockReduceSum(d0 * d0 + d1 * d1 + d2 * d2);
    float dt = tval - mu;
    float var = (ss + (hasT ? dt * dt : 0.f)) / cnt;
    float rs = rsqrtf(var + EPS_LN);
#pragma unroll
    for (int q = 0; q < 3; ++q) {
        int c = tid + 256 * q;
        float v = (xv[q] - mu) * rs * w[c] + bb[c];
        if (obf16) ((ushortT*)Y)[(size_t)orow * Cc + c] = f2bf(v);
        else       ((float*)Y)[(size_t)orow * Cc + c] = v;
    }
    if (hasT && tid == 0) yt[orow] = dt * rs * w[Cc] + bb[Cc];
}

// ---------------- MFMA GEMM: C = A[M,K](bf16) @ Bt[N,K](bf16)^T -----------
// BK=64, XOR-swizzled LDS. EPI: 0 = bias(+rank1) -> bf16 ;
// 1 = gelu(bias+rank1) -> bf16 ; 4 = split-K partial fp32
template <int EPI>
__global__ __launch_bounds__(256)
void gemm_bt(const ushortT* __restrict__ A, int lda,
             const ushortT* __restrict__ Bt, int ldb,
             void* __restrict__ Cm, int ldc, int K,
             const float* __restrict__ bias,
             const float* __restrict__ extraA,
             const float* __restrict__ extraB)
{
    __shared__ __align__(16) ushortT Als[128 * 64];   // 16 KB, swizzled linear
    __shared__ __align__(16) ushortT Bls[128 * 64];   // 16 KB
    if (EPI == 4) {
        int koff = blockIdx.z * K;
        A += koff; Bt += koff;
    }
    int tid = threadIdx.x;
    int lane = tid & 63, wid = tid >> 6;
    int wm = wid >> 1, wn = wid & 1;
    int m0 = blockIdx.y * 128, n0 = blockIdx.x * 128;
    f32x4 acc[4][4];
    const f32x4 fz = {0.f, 0.f, 0.f, 0.f};
#pragma unroll
    for (int i = 0; i < 4; ++i)
#pragma unroll
        for (int j = 0; j < 4; ++j) acc[i][j] = fz;

    for (int k0 = 0; k0 < K; k0 += 64) {
#pragma unroll
        for (int is = 0; is < 4; ++is) {
            int ch = is * 256 + tid;              // 0..1023
            int m = ch >> 3;
            int kc8 = (ch & 7) ^ (m & 7);         // pre-swizzled source chunk
            gll16(A + (size_t)(m0 + m) * lda + k0 + kc8 * 8, Als + ch * 8);
            gll16(Bt + (size_t)(n0 + m) * ldb + k0 + kc8 * 8, Bls + ch * 8);
        }
        __syncthreads();
#pragma unroll
        for (int kk = 0; kk < 2; ++kk) {
            int cidx = kk * 4 + (lane >> 4);
            bf16x8 af[4], bfv[4];
#pragma unroll
            for (int i = 0; i < 4; ++i) {
                int row = wm * 64 + i * 16 + (lane & 15);
                af[i] = *(const bf16x8*)(Als + ((size_t)row * 8 + (cidx ^ (row & 7))) * 8);
                int col = wn * 64 + i * 16 + (lane & 15);
                bfv[i] = *(const bf16x8*)(Bls + ((size_t)col * 8 + (cidx ^ (col & 7))) * 8);
            }
#pragma unroll
            for (int i = 0; i < 4; ++i)
#pragma unroll
                for (int j = 0; j < 4; ++j)
                    acc[i][j] = __builtin_amdgcn_mfma_f32_16x16x32_bf16(af[i], bfv[j], acc[i][j], 0, 0, 0);
        }
        __syncthreads();
    }
#pragma unroll
    for (int i = 0; i < 4; ++i) {
#pragma unroll
        for (int j = 0; j < 4; ++j) {
#pragma unroll
            for (int r = 0; r < 4; ++r) {
                int row = m0 + wm * 64 + i * 16 + (lane >> 4) * 4 + r;
                int col = n0 + wn * 64 + j * 16 + (lane & 15);
                float v = acc[i][j][r];
                if (extraA) v += extraA[row] * extraB[col];
                if (bias) v += bias[col];
                size_t oi = (size_t)row * ldc + col;
                if (EPI == 0) {
                    ((ushortT*)Cm)[oi] = f2bf(v);
                } else if (EPI == 1) {
                    v = 0.5f * v * (1.f + erff(v * 0.70710678118654752440f));
                    ((ushortT*)Cm)[oi] = f2bf(v);
                } else if (EPI == 4) {
                    ((float*)Cm)[(size_t)blockIdx.z * ((size_t)BTc * Cc) + oi] = v;
                }
            }
        }
    }
}

// ===== fused QK + softmax + Sinkhorn + PV (per-head-eighth block) ==========
// grid = 192 blocks x 512 threads. Block (n = gb%24, r = gb/24) owns rows
// [r*64, r*64+64) of head n; all 8 blocks of head n land on XCD n%8.
// Exchange protocol (R18-proven): tid0 fence+add+poll, syncthreads broadcast.
__global__ __launch_bounds__(512)
void sinkfused(const ushortT* __restrict__ qkvb, ushortT* __restrict__ y,
               float* __restrict__ partials, unsigned* __restrict__ ctr,
               unsigned barBase)
{
    int gb = blockIdx.x;
    int n = gb % NHc, r = gb / NHc;
    int row0 = r * 64;
    int b = n / Hc, h = n - b * Hc;
    int tid = threadIdx.x;
    int l = tid & 63, w = tid >> 6;              // 8 waves
    int wm = w >> 1, wn = w & 1;                 // 4 row-groups x 2 col-groups
    __shared__ __align__(16) ushortT Els[64][ELP];    // 66.6 KB (padded)
    __shared__ __align__(16) ushortT Kshare[64 * VLP]; // 17.4 KB (scratch / PV V)
    __shared__ float a_s[64];
    __shared__ float b_s[Tc];
    __shared__ float smx[2][64], ssum[2][64], srs[2][64];
    const f32x4 fz = {0.f, 0.f, 0.f, 0.f};

    // ---- phase QK: scores for own 64 rows x (r+1)*64 cols ----
    int qrow = b * Tc + row0 + wm * 16 + (l & 15);
    const ushortT* qp = qkvb + (size_t)qrow * C3 + h * HDc + (l >> 4) * 8;
    bf16x8 aq0 = *(const bf16x8*)(qp);
    bf16x8 aq1 = *(const bf16x8*)(qp + 32);

    int nT2 = (r + 1) * 2;                       // col-tiles per wn (<=16)
    f32x4 acc[16];
#pragma unroll
    for (int j = 0; j < 16; ++j) acc[j] = fz;

    // stage ALL K rows [0, (r+1)*64) swizzled into Els region (<=64KB)
    ushortT* EK = &Els[0][0];
    {
        int nch = (r + 1) * 512;                  // rows*8 chunks
        for (int ch = tid; ch < nch; ch += 512) {
            int row = ch >> 3, c16 = (ch & 7) ^ (row & 7);
            gll16(qkvb + (size_t)(b * Tc + row) * C3 + Cc + h * HDc + c16 * 8,
                  EK + ch * 8);
        }
    }
    __syncthreads();
#pragma unroll
    for (int t = 0; t < 16; ++t) {
        if (t < nT2) {
            int krow = (2 * t + wn) * 16 + (l & 15);
            int c16a = (l >> 4);
            int c16b = 4 + (l >> 4);
            bf16x8 bk0 = *(const bf16x8*)(EK + ((size_t)krow * 8 + (c16a ^ (krow & 7))) * 8);
            bf16x8 bk1 = *(const bf16x8*)(EK + ((size_t)krow * 8 + (c16b ^ (krow & 7))) * 8);
            acc[t] = __builtin_amdgcn_mfma_f32_16x16x32_bf16(aq0, bk0, acc[t], 0, 0, 0);
            acc[t] = __builtin_amdgcn_mfma_f32_16x16x32_bf16(aq1, bk1, acc[t], 0, 0, 0);
        }
    }
    __syncthreads();   // all EK reads done before Els is overwritten below

    // ---- causal softmax (rows split across wn pairs) -> E, rowsum -> a1 --
    int colbase = (l & 15);
    int lrow4 = wm * 16 + (l >> 4) * 4;          // local row base for e=0..3
    int rowa[4];
#pragma unroll
    for (int e = 0; e < 4; ++e) rowa[e] = row0 + lrow4 + e;

    float mx[4] = {-INFINITY, -INFINITY, -INFINITY, -INFINITY};
#pragma unroll
    for (int t = 0; t < 16; ++t) {
        if (t < nT2) {
            int col = (2 * t + wn) * 16 + colbase;
#pragma unroll
            for (int e = 0; e < 4; ++e)
                if (col <= rowa[e]) mx[e] = fmaxf(mx[e], acc[t][e] * 0.125f);
        }
    }
#pragma unroll
    for (int e = 0; e < 4; ++e)
        for (int o = 1; o < 16; o <<= 1) mx[e] = fmaxf(mx[e], __shfl_xor(mx[e], o));
    if ((l & 15) == 0)
#pragma unroll
        for (int e = 0; e < 4; ++e) smx[wn][lrow4 + e] = mx[e];
    __syncthreads();
#pragma unroll
    for (int e = 0; e < 4; ++e)
        mx[e] = fmaxf(smx[0][lrow4 + e], smx[1][lrow4 + e]);

    float se[4] = {0.f, 0.f, 0.f, 0.f};
#pragma unroll
    for (int t = 0; t < 16; ++t) {
        if (t < nT2) {
            int col = (2 * t + wn) * 16 + colbase;
#pragma unroll
            for (int e = 0; e < 4; ++e) {
                float exv = (col <= rowa[e]) ? __expf(acc[t][e] * 0.125f - mx[e]) : 0.f;
                acc[t][e] = exv;
                se[e] += exv;
            }
        }
    }
#pragma unroll
    for (int e = 0; e < 4; ++e)
        for (int o = 1; o < 16; o <<= 1) se[e] += __shfl_xor(se[e], o);
    if ((l & 15) == 0)
#pragma unroll
        for (int e = 0; e < 4; ++e) ssum[wn][lrow4 + e] = se[e];
    __syncthreads();
    float inv[4];
#pragma unroll
    for (int e = 0; e < 4; ++e)
        inv[e] = 1.f / (ssum[0][lrow4 + e] + ssum[1][lrow4 + e]);

    float rsum[4] = {0.f, 0.f, 0.f, 0.f};
#pragma unroll
    for (int t = 0; t < 16; ++t) {
        if (t < nT2) {
            int col = (2 * t + wn) * 16 + colbase;
#pragma unroll
            for (int e = 0; e < 4; ++e) {
                float Ee = __expf(-(acc[t][e] * inv[e]));   // masked: exp(-0)=1
                rsum[e] += Ee;
                Els[lrow4 + e][col] = f2bf(Ee);
            }
        }
    }
#pragma unroll
    for (int e = 0; e < 4; ++e)
        for (int o = 1; o < 16; o <<= 1) rsum[e] += __shfl_xor(rsum[e], o);
    if ((l & 15) == 0)
#pragma unroll
        for (int e = 0; e < 4; ++e) srs[wn][lrow4 + e] = rsum[e];
    __syncthreads();
    if (wn == 0 && (l & 15) == 0) {
        float tail = (float)(Tc - (r + 1) * 64);
#pragma unroll
        for (int e = 0; e < 4; ++e)
            a_s[lrow4 + e] = INVN / (srs[0][lrow4 + e] + srs[1][lrow4 + e] + tail);
    }
    // fill fully-masked tail with ones
    {
        int tailc = 64 - (r + 1) * 8;             // us8 chunks per row
        if (tailc > 0) {
            us8 ones8;
#pragma unroll
            for (int e = 0; e < 8; ++e) ones8[e] = 0x3F80;
            for (int idx2 = tid; idx2 < 64 * tailc; idx2 += 512) {
                int rr = idx2 / tailc, cc = idx2 - rr * tailc;
                *(us8*)&Els[rr][((r + 1) * 8 + cc) * 8] = ones8;
            }
        }
    }
    __syncthreads();

    float* mypart = partials + (size_t)(n * SBQ + r) * Tc;
    const float* hpart = partials + (size_t)n * SBQ * Tc;
    unsigned* myctr = ctr + n * 16;              // 64B-padded per-head counter
    float* scr = (float*)Kshare;                 // 8 x 512 fp32 col-pass scratch

    // ---- 11 alternating passes: col(0),row(1),...,col(10) ----
#pragma unroll 1
    for (int p = 0; p < 11; ++p) {
        if ((p & 1) == 0) {
            // col partial over own 64 rows — vectorized us8 + scratch reduce
            int cg = tid & 63, sl = tid >> 6;
            float ac[8] = {0.f, 0.f, 0.f, 0.f, 0.f, 0.f, 0.f, 0.f};
#pragma unroll
            for (int i = 0; i < 8; ++i) {
                int row = sl * 8 + i;
                us8 ev = *(const us8*)&Els[row][cg * 8];
                float fa = a_s[row];
#pragma unroll
                for (int e = 0; e < 8; ++e)
                    ac[e] += bf2f(ev[e]) * fa;
            }
            f32x4 lo = {ac[0], ac[1], ac[2], ac[3]};
            f32x4 hi = {ac[4], ac[5], ac[6], ac[7]};
            *(f32x4*)&scr[sl * 512 + cg * 8] = lo;
            *(f32x4*)&scr[sl * 512 + cg * 8 + 4] = hi;
            __syncthreads();
            int j = tid;
            float accs = 0.f;
#pragma unroll
            for (int s2 = 0; s2 < 8; ++s2) accs += scr[s2 * 512 + j];
            __hip_atomic_store(&mypart[j], accs, __ATOMIC_RELAXED, __HIP_MEMORY_SCOPE_AGENT);
            __syncthreads();
            if (tid == 0) {
                __threadfence();
                atomicAdd(myctr, 1u);
                unsigned tgt = barBase + (unsigned)(p / 2 + 1) * SBQ;
                while (__hip_atomic_load(myctr, __ATOMIC_ACQUIRE, __HIP_MEMORY_SCOPE_AGENT) < tgt)
                    __builtin_amdgcn_s_sleep(2);
            }
            __syncthreads();
            float accs2 = 0.f;
#pragma unroll
            for (int s2 = 0; s2 < SBQ; ++s2)
                accs2 += __hip_atomic_load(&hpart[s2 * Tc + j], __ATOMIC_RELAXED, __HIP_MEMORY_SCOPE_AGENT);
            b_s[j] = INVN / accs2;
            __syncthreads();
        } else {
            // row pass on own rows: wave per 8 rows, ILP 4
            f32x4 b0 = *(const f32x4*)&b_s[l * 8];
            f32x4 b1 = *(const f32x4*)&b_s[l * 8 + 4];
            float breg[8] = {b0[0], b0[1], b0[2], b0[3], b1[0], b1[1], b1[2], b1[3]};
#pragma unroll 1
            for (int k = 0; k < 8; k += 4) {
                int r0 = w * 8 + k;
                u32x4 q0 = *(const u32x4*)(&Els[r0 + 0][l * 8]);
                u32x4 q1 = *(const u32x4*)(&Els[r0 + 1][l * 8]);
                u32x4 q2 = *(const u32x4*)(&Els[r0 + 2][l * 8]);
                u32x4 q3 = *(const u32x4*)(&Els[r0 + 3][l * 8]);
                float s0 = 0.f, s1 = 0.f, s2 = 0.f, s3 = 0.f;
#pragma unroll
                for (int c = 0; c < 4; ++c) {
                    s0 += bflo(q0[c]) * breg[2 * c] + bfhi(q0[c]) * breg[2 * c + 1];
                    s1 += bflo(q1[c]) * breg[2 * c] + bfhi(q1[c]) * breg[2 * c + 1];
                    s2 += bflo(q2[c]) * breg[2 * c] + bfhi(q2[c]) * breg[2 * c + 1];
                    s3 += bflo(q3[c]) * breg[2 * c] + bfhi(q3[c]) * breg[2 * c + 1];
                }
                s0 = waveReduceSumX(s0);
                s1 = waveReduceSumX(s1);
                s2 = waveReduceSumX(s2);
                s3 = waveReduceSumX(s3);
                if (l == 0) {
                    a_s[r0 + 0] = INVN / s0;
                    a_s[r0 + 1] = INVN / s1;
                    a_s[r0 + 2] = INVN / s2;
                    a_s[r0 + 3] = INVN / s3;
                }
            }
            __syncthreads();
        }
    }

    // ---- PV (local, 128-t chunks): y = a6 ⊙ (E_own @ (n·b6 ⊙ V)) ---------
    {
        ushortT* Kls2 = Kshare;                  // [64 d][136 t-pad] bf16
        f32x4 acc2[2];
#pragma unroll
        for (int j = 0; j < 2; ++j) acc2[j] = fz;
        const ushortT* vbase = qkvb + (size_t)(b * Tc) * C3 + 2 * Cc + h * HDc;

#pragma unroll 1
        for (int k0 = 0; k0 < Tc; k0 += 128) {
            // stage chunk: 128 t x 64 d, scaled by n*b6[t], transposed
#pragma unroll
            for (int ii = 0; ii < 2; ++ii) {
                int ch = ii * 512 + tid;          // 0..1023
                int tt = ch >> 3, dblk = ch & 7;
                us8 vv = *(const us8*)(vbase + (size_t)(k0 + tt) * C3 + dblk * 8);
                float bs = 512.f * b_s[k0 + tt];
#pragma unroll
                for (int e = 0; e < 8; ++e)
                    Kls2[(dblk * 8 + e) * VLP + tt] = f2bf(bf2f(vv[e]) * bs);
            }
            __syncthreads();
#pragma unroll
            for (int kk = 0; kk < 128; kk += 32) {
                bf16x8 af = *(const bf16x8*)&Els[wm * 16 + (l & 15)][k0 + kk + (l >> 4) * 8];
#pragma unroll
                for (int j = 0; j < 2; ++j) {
                    bf16x8 bv = *(const bf16x8*)(Kls2 + (size_t)(wn * 32 + j * 16 + (l & 15)) * VLP + kk + (l >> 4) * 8);
                    acc2[j] = __builtin_amdgcn_mfma_f32_16x16x32_bf16(af, bv, acc2[j], 0, 0, 0);
                }
            }
            __syncthreads();
        }
#pragma unroll
        for (int j = 0; j < 2; ++j)
#pragma unroll
            for (int rr = 0; rr < 4; ++rr) {
                int lrow = wm * 16 + (l >> 4) * 4 + rr;
                float a_r = a_s[lrow];
                int grow = b * Tc + row0 + lrow;
                int gcol = h * HDc + wn * 32 + j * 16 + (l & 15);
                y[(size_t)grow * Cc + gcol] = f2bf(acc2[j][rr] * a_r);
            }
    }
}

// ------- split-K reduce + bias (+opt Euler) + LN (fused) ------------------
__global__ __launch_bounds__(256)
void reduce_ln(const float* __restrict__ parts, const float* __restrict__ bias,
               float* __restrict__ z, const float* __restrict__ lnw,
               const float* __restrict__ lnb, ushortT* __restrict__ xlnb,
               float* __restrict__ xt, float tval, int doEuler)
{
    int row = blockIdx.x, tid = threadIdx.x;
    const size_t CS = (size_t)BTc * Cc;
    float v[3];
#pragma unroll
    for (int q = 0; q < 3; ++q) {
        int c = tid + 256 * q;
        size_t idx = (size_t)row * Cc + c;
        float s = parts[idx] + parts[CS + idx] + parts[2 * CS + idx]
                + parts[3 * CS + idx] + bias[c];
        if (doEuler) {
            v[q] = z[idx] + H_STEP * s;
            z[idx] = v[q];
        } else {
            v[q] = s;
        }
    }
    float s = blockReduceSum(v[0] + v[1] + v[2]);
    float mu = (s + tval) / 769.f;
    float d0 = v[0] - mu, d1 = v[1] - mu, d2 = v[2] - mu;
    float ss = blockReduceSum(d0 * d0 + d1 * d1 + d2 * d2);
    float dt = tval - mu;
    float var = (ss + dt * dt) / 769.f;
    float rs = rsqrtf(var + EPS_LN);
#pragma unroll
    for (int q = 0; q < 3; ++q) {
        int c = tid + 256 * q;
        xlnb[(size_t)row * Cc + c] = f2bf((v[q] - mu) * rs * lnw[c] + lnb[c]);
    }
    if (tid == 0) xt[row] = dt * rs * lnw[Cc] + lnb[Cc];
}

// ---------------- logits: out[b,v] = xf[b,:] . wte[v,:] (fp32, f32x4) -----
__global__ __launch_bounds__(256)
void logits_kernel(const float* __restrict__ xf, const float* __restrict__ wte,
                   float* __restrict__ out)
{
    __shared__ __align__(16) float xs[2 * Cc];
    int tid = threadIdx.x;
    for (int i = tid; i < 384; i += 256)
        ((f32x4*)xs)[i] = ((const f32x4*)xf)[i];
    __syncthreads();
    int w = tid >> 6, lane = tid & 63;
    int vrow = blockIdx.x * 4 + w;
    const f32x4* wr = (const f32x4*)(wte + (size_t)vrow * Cc);
    const f32x4* x0 = (const f32x4*)xs;
    const f32x4* x1 = (const f32x4*)(xs + Cc);
    float a0 = 0.f, a1 = 0.f;
#pragma unroll
    for (int it = 0; it < 3; ++it) {
        int k4 = it * 64 + lane;
        f32x4 wv = wr[k4];
        f32x4 p = x0[k4], q = x1[k4];
        a0 += wv[0] * p[0] + wv[1] * p[1] + wv[2] * p[2] + wv[3] * p[3];
        a1 += wv[0] * q[0] + wv[1] * q[1] + wv[2] * q[2] + wv[3] * q[3];
    }
    for (int o = 32; o; o >>= 1) {
        a0 += __shfl_down(a0, o);
        a1 += __shfl_down(a1, o);
    }
    if (lane == 0) {
        out[vrow] = a0;
        out[Vc + vrow] = a1;
    }
}

// ==========================================================================
extern "C" void kernel_launch(void* const* d_in, const int* in_sizes, int n_in,
                              void* d_out, int out_size, void* d_ws, size_t ws_size,
                              hipStream_t stream)
{
    const int*   idx        = (const int*)  d_in[0];
    const float* wte        = (const float*)d_in[1];
    const float* wpe        = (const float*)d_in[2];
    const float* attn_ln_w  = (const float*)d_in[3];
    const float* attn_ln_b  = (const float*)d_in[4];
    const float* c_attn_w   = (const float*)d_in[5];
    const float* c_attn_b   = (const float*)d_in[6];
    const float* c_proj_w   = (const float*)d_in[7];
    const float* c_proj_b   = (const float*)d_in[8];
    const float* mlp_ln_w   = (const float*)d_in[9];
    const float* mlp_ln_b   = (const float*)d_in[10];
    const float* c_fc_w     = (const float*)d_in[11];
    const float* c_fc_b     = (const float*)d_in[12];
    const float* mlp_proj_w = (const float*)d_in[13];
    const float* mlp_proj_b = (const float*)d_in[14];
    const float* lnf_w      = (const float*)d_in[15];
    const float* lnf_b      = (const float*)d_in[16];
    float* out = (float*)d_out;

    // -------- workspace carving (256B aligned) --------
    char* base = (char*)d_ws;
    size_t off = 0;
    auto alloc = [&](size_t bytes) -> void* {
        void* p = base + off;
        off = (off + bytes + 255) & ~(size_t)255;
        return p;
    };
    float*   z     = (float*)  alloc((size_t)BTc * Cc * 4);
    float*   parts = (float*)  alloc((size_t)4 * BTc * Cc * 4);   // split-K partials
    ushortT* qkvb  = (ushortT*)alloc((size_t)BTc * C3 * 2);
    ushortT* xlnb  = (ushortT*)alloc((size_t)BTc * Cc * 2);
    ushortT* y     = (ushortT*)alloc((size_t)BTc * Cc * 2);
    ushortT* h1    = (ushortT*)alloc((size_t)BTc * C4 * 2);
    float*   xt    = (float*)  alloc(BTc * 4);
    float*   partv = (float*)  alloc((size_t)NHc * SBQ * Tc * 4);
    unsigned* ctr  = (unsigned*)alloc(NHc * 16 * 4);
    float*   xf    = (float*)  alloc(2 * Cc * 4);
    ushortT* WqkvT = (ushortT*)alloc((size_t)C3 * Cc * 2);
    ushortT* WprojT= (ushortT*)alloc((size_t)Cc * Cc * 2);
    ushortT* WfcT  = (ushortT*)alloc((size_t)C4 * Cc * 2);
    ushortT* WmlpT = (ushortT*)alloc((size_t)Cc * C4 * 2);

    hipMemsetAsync(ctr, 0, NHc * 16 * 4, stream);
    embed_ln<<<BTc, 256, 0, stream>>>(idx, wte, wpe, z, attn_ln_w, attn_ln_b, xlnb, xt);
    wtrans_kernel<<<dim3(Cc / 32, C3 / 32), 256, 0, stream>>>(c_attn_w,   WqkvT,  Cc, C3);
    wtrans_kernel<<<dim3(Cc / 32, Cc / 32), 256, 0, stream>>>(c_proj_w,   WprojT, Cc, Cc);
    wtrans_kernel<<<dim3(Cc / 32, C4 / 32), 256, 0, stream>>>(c_fc_w,     WfcT,   Cc, C4);
    wtrans_kernel<<<dim3(C4 / 32, Cc / 32), 256, 0, stream>>>(mlp_proj_w, WmlpT,  C4, Cc);

    float t = 0.f;
    for (int step = 0; step < 20; ++step) {
        gemm_bt<0><<<dim3(C3 / 128, BTc / 128), 256, 0, stream>>>(
            xlnb, Cc, WqkvT, Cc, qkvb, C3, Cc,
            c_attn_b, xt, c_attn_w + (size_t)Cc * C3);
        sinkfused<<<NHc * SBQ, 512, 0, stream>>>(
            qkvb, y, partv, ctr, (unsigned)(step * 6 * SBQ));
        gemm_bt<4><<<dim3(Cc / 128, BTc / 128, 4), 256, 0, stream>>>(
            y, Cc, WprojT, Cc, parts, Cc, Cc / 4,
            nullptr, nullptr, nullptr);
        reduce_ln<<<BTc, 256, 0, stream>>>(parts, c_proj_b, nullptr,
                                           mlp_ln_w, mlp_ln_b, xlnb, xt, t, 0);
        gemm_bt<1><<<dim3(C4 / 128, BTc / 128), 256, 0, stream>>>(
            xlnb, Cc, WfcT, Cc, h1, C4, Cc,
            c_fc_b, xt, c_fc_w + (size_t)Cc * C4);
        gemm_bt<4><<<dim3(Cc / 128, BTc / 128, 4), 256, 0, stream>>>(
            h1, C4, WmlpT, C4, parts, Cc, C4 / 4,
            nullptr, nullptr, nullptr);
        t += H_STEP;
        reduce_ln<<<BTc, 256, 0, stream>>>(parts, mlp_proj_b, z,
                                           attn_ln_w, attn_ln_b, xlnb, xt, t, 1);
    }

    ln_kernel<<<2, 256, 0, stream>>>(z, lnf_w, lnf_b, xf, nullptr, 0, 0.f, Tc, Tc - 1, 0, 0);
    logits_kernel<<<Vc / 4, 256, 0, stream>>>(xf, wte, out);
}